// Round 2
// baseline (244.931 us; speedup 1.0000x reference)
//
#include <hip/hip_runtime.h>
#include <hip/hip_bf16.h>
#include <stdint.h>

// Workload (fixed):
//   x:            [B=32, L=4096, D=768] f32 (shape only)
//   topic_vectors:[T=2048, D=768] f32
//   out:          [B, L, T] f32 -- 1 GiB, batch-broadcast of a [L,T] 0/1 map.
// softmax is monotone -> top_k(softmax(tv)) indices == top_k(tv) indices;
// indices < D=768 so `% L` is identity -> rows l >= 768 are all zero.
//
// Roofline: 1.074 GB of mandatory output writes; harness memset sustains
// ~6.6 TB/s on this buffer -> ~165 us floor for the fill.

#define B_DIM    32
#define L_DIM    4096
#define D_DIM    768
#define T_TOPICS 2048
#define K_TOP    16

#define WORDS_PER_ROW (T_TOPICS / 32)            // 64 u32 words of topic-bits per l-row
#define BITMAP_WORDS  (D_DIM * WORDS_PER_ROW)    // 49152 words = 192 KiB
#define Q_TOTAL   (L_DIM * (T_TOPICS / 4))       // float4s per batch plane = 2,097,152
#define B_STRIDE4 (L_DIM * (T_TOPICS / 4))       // batch stride in float4 units

typedef float f32x4 __attribute__((ext_vector_type(4)));

__global__ void zero_bitmap_kernel(uint32_t* __restrict__ bm) {
    int i = blockIdx.x * blockDim.x + threadIdx.x;
    if (i < BITMAP_WORDS) bm[i] = 0u;
}

// One wave (64 lanes) per topic. Each lane holds 12 of the 768 values.
// 16 iterations of wave-argmax (tie -> smaller index, matching jax top_k),
// knock out winner, lane 0 sets bit (l=idx, t=topic) in [D_DIM][T_TOPICS] bitmap.
__global__ void topk_kernel(const float* __restrict__ tv, uint32_t* __restrict__ bm) {
    const int t    = blockIdx.x;        // topic id
    const int lane = threadIdx.x;       // 0..63
    const float* __restrict__ row = tv + (size_t)t * D_DIM;

    float v[D_DIM / 64];                // 12 values, idx = lane + j*64 (coalesced)
    #pragma unroll
    for (int j = 0; j < D_DIM / 64; ++j) v[j] = row[lane + j * 64];

    for (int k = 0; k < K_TOP; ++k) {
        // local argmax; ascending j + strict '>' keeps smallest index on ties
        float bv = v[0];
        int   bj = 0;
        #pragma unroll
        for (int j = 1; j < D_DIM / 64; ++j) {
            if (v[j] > bv) { bv = v[j]; bj = j; }
        }
        float cv = bv;
        int   ci = lane + bj * 64;
        #pragma unroll
        for (int off = 32; off > 0; off >>= 1) {
            float ov = __shfl_xor(cv, off);
            int   oi = __shfl_xor(ci, off);
            if (ov > cv || (ov == cv && oi < ci)) { cv = ov; ci = oi; }
        }
        if ((ci & 63) == lane) v[ci >> 6] = -INFINITY;
        if (lane == 0) {
            atomicOr(&bm[ci * WORDS_PER_ROW + (t >> 5)], 1u << (t & 31));
        }
    }
}

// Each thread owns one (l, t4) float4 of the [L,T] map: <=1 bitmap load +
// a few ALU ops, then 32 coalesced nontemporal 16B stores (one per batch
// plane, 32 MB apart). Exact cover: 8192 blocks x 256 threads == Q_TOTAL.
__global__ __launch_bounds__(256) void fill_kernel(const uint32_t* __restrict__ bm,
                                                   f32x4* __restrict__ out) {
    const unsigned q  = blockIdx.x * 256u + threadIdx.x;   // 0..Q_TOTAL-1
    const int l  = (int)(q >> 9);                          // 0..4095
    const int t4 = (int)(q & 511u);                        // 0..511

    uint32_t w = 0u;
    if (l < D_DIM) w = bm[l * WORDS_PER_ROW + (t4 >> 3)];
    const int sh = (t4 & 7) * 4;

    f32x4 val;
    val.x = ((w >> (sh + 0)) & 1u) ? 1.0f : 0.0f;
    val.y = ((w >> (sh + 1)) & 1u) ? 1.0f : 0.0f;
    val.z = ((w >> (sh + 2)) & 1u) ? 1.0f : 0.0f;
    val.w = ((w >> (sh + 3)) & 1u) ? 1.0f : 0.0f;

    f32x4* p = out + q;
    #pragma unroll
    for (int b = 0; b < B_DIM; ++b) {
        __builtin_nontemporal_store(val, p);
        p += (size_t)B_STRIDE4;
    }
}

extern "C" void kernel_launch(void* const* d_in, const int* in_sizes, int n_in,
                              void* d_out, int out_size, void* d_ws, size_t ws_size,
                              hipStream_t stream) {
    const float* tv  = (const float*)d_in[1];   // topic_vectors [T, D]
    f32x4*       out = (f32x4*)d_out;           // [B, L, T] f32
    uint32_t*    bm  = (uint32_t*)d_ws;         // 192 KiB bitmap

    hipLaunchKernelGGL(zero_bitmap_kernel,
                       dim3((BITMAP_WORDS + 255) / 256), dim3(256), 0, stream, bm);
    hipLaunchKernelGGL(topk_kernel,
                       dim3(T_TOPICS), dim3(64), 0, stream, tv, bm);
    hipLaunchKernelGGL(fill_kernel,
                       dim3(Q_TOTAL / 256), dim3(256), 0, stream, bm, out);
}

// Round 3
// 216.446 us; speedup vs baseline: 1.1316x; 1.1316x over previous
//
#include <hip/hip_runtime.h>
#include <hip/hip_bf16.h>
#include <stdint.h>

// Workload (fixed):
//   x:            [B=32, L=4096, D=768] f32 (shape only)
//   topic_vectors:[T=2048, D=768] f32
//   out:          [B, L, T] f32 -- 1 GiB, batch-broadcast of a [L,T] 0/1 map.
// softmax monotone -> top_k(softmax(tv)) idx == top_k(tv) idx; idx < D=768 so
// `% L` is identity -> rows l >= 768 are all zero (80% of output).
//
// Roofline: 1.074 GB mandatory writes; memset sustains ~6.5 TB/s -> ~165 us.
// Strategy: pure-store memset-clone for the zero region (859 MB), bitmap-
// predicated fill only for l < 768 (215 MB). Sequential addresses per plane.

#define B_DIM    32
#define L_DIM    4096
#define D_DIM    768
#define T_TOPICS 2048
#define K_TOP    16

#define WORDS_PER_ROW (T_TOPICS / 32)            // 64 u32 per l-row
#define BITMAP_WORDS  (D_DIM * WORDS_PER_ROW)    // 49152 words = 192 KiB
#define PLANE4   (L_DIM * (T_TOPICS / 4))        // float4 per batch plane = 2,097,152
#define BMREG4   (D_DIM * (T_TOPICS / 4))        // float4 in rows [0,768)   =   393,216
#define ZREG4    (PLANE4 - BMREG4)               // float4 in rows [768,4096)= 1,703,936

typedef float f32x4 __attribute__((ext_vector_type(4)));

__global__ void zero_bitmap_kernel(uint32_t* __restrict__ bm) {
    int i = blockIdx.x * blockDim.x + threadIdx.x;
    if (i < BITMAP_WORDS) bm[i] = 0u;
}

// One wave per topic; 16x wave-argmax (tie -> smaller index, = jax top_k),
// set bit (l=idx, t=topic) in the [D_DIM][T_TOPICS] bitmap.
__global__ void topk_kernel(const float* __restrict__ tv, uint32_t* __restrict__ bm) {
    const int t    = blockIdx.x;
    const int lane = threadIdx.x;
    const float* __restrict__ row = tv + (size_t)t * D_DIM;

    float v[D_DIM / 64];                 // 12 values, idx = lane + j*64
    #pragma unroll
    for (int j = 0; j < D_DIM / 64; ++j) v[j] = row[lane + j * 64];

    for (int k = 0; k < K_TOP; ++k) {
        float bv = v[0];
        int   bj = 0;
        #pragma unroll
        for (int j = 1; j < D_DIM / 64; ++j) {
            if (v[j] > bv) { bv = v[j]; bj = j; }
        }
        float cv = bv;
        int   ci = lane + bj * 64;
        #pragma unroll
        for (int off = 32; off > 0; off >>= 1) {
            float ov = __shfl_xor(cv, off);
            int   oi = __shfl_xor(ci, off);
            if (ov > cv || (ov == cv && oi < ci)) { cv = ov; ci = oi; }
        }
        if ((ci & 63) == lane) v[ci >> 6] = -INFINITY;
        if (lane == 0) {
            atomicOr(&bm[ci * WORDS_PER_ROW + (t >> 5)], 1u << (t & 31));
        }
    }
}

// A: zero region, rows [768, 4096) of every plane. Pure stores, no loads,
// no branches. grid (ZREG4/1024 = 1664, 32); 4 x 1KB-coalesced stores/wave.
__global__ __launch_bounds__(256) void fill_zero_kernel(f32x4* __restrict__ out) {
    const f32x4 z = {0.f, 0.f, 0.f, 0.f};
    f32x4* p = out + (size_t)blockIdx.y * PLANE4
                   + (size_t)BMREG4 + blockIdx.x * 1024u + threadIdx.x;
    p[0]   = z;
    p[256] = z;
    p[512] = z;
    p[768] = z;
}

// B: bitmap region, rows [0, 768). grid (BMREG4/1024 = 384, 32).
// Per store: idx in plane -> l = idx>>9, t4 = idx&511; one hot-L2 dword load.
__global__ __launch_bounds__(256) void fill_bm_kernel(const uint32_t* __restrict__ bm,
                                                      f32x4* __restrict__ out) {
    f32x4* plane = out + (size_t)blockIdx.y * PLANE4;
    const unsigned base = blockIdx.x * 1024u + threadIdx.x;
    #pragma unroll
    for (int s = 0; s < 4; ++s) {
        const unsigned idx = base + s * 256u;        // < 393,216 -> l < 768
        const int l  = (int)(idx >> 9);
        const int t4 = (int)(idx & 511u);
        const uint32_t w  = bm[l * WORDS_PER_ROW + (t4 >> 3)];
        const int sh = (t4 & 7) * 4;
        f32x4 val;
        val.x = ((w >> (sh + 0)) & 1u) ? 1.0f : 0.0f;
        val.y = ((w >> (sh + 1)) & 1u) ? 1.0f : 0.0f;
        val.z = ((w >> (sh + 2)) & 1u) ? 1.0f : 0.0f;
        val.w = ((w >> (sh + 3)) & 1u) ? 1.0f : 0.0f;
        plane[idx] = val;
    }
}

extern "C" void kernel_launch(void* const* d_in, const int* in_sizes, int n_in,
                              void* d_out, int out_size, void* d_ws, size_t ws_size,
                              hipStream_t stream) {
    const float* tv  = (const float*)d_in[1];   // topic_vectors [T, D]
    f32x4*       out = (f32x4*)d_out;           // [B, L, T] f32
    uint32_t*    bm  = (uint32_t*)d_ws;         // 192 KiB bitmap

    hipLaunchKernelGGL(zero_bitmap_kernel,
                       dim3((BITMAP_WORDS + 255) / 256), dim3(256), 0, stream, bm);
    hipLaunchKernelGGL(topk_kernel,
                       dim3(T_TOPICS), dim3(64), 0, stream, tv, bm);
    hipLaunchKernelGGL(fill_bm_kernel,
                       dim3(BMREG4 / 1024, B_DIM), dim3(256), 0, stream, bm, out);
    hipLaunchKernelGGL(fill_zero_kernel,
                       dim3(ZREG4 / 1024, B_DIM), dim3(256), 0, stream, out);
}

// Round 4
// 215.561 us; speedup vs baseline: 1.1362x; 1.0041x over previous
//
#include <hip/hip_runtime.h>
#include <hip/hip_bf16.h>
#include <stdint.h>

// Workload (fixed):
//   x:            [B=32, L=4096, D=768] f32 (shape only)
//   topic_vectors:[T=2048, D=768] f32
//   out:          [B, L, T] f32 -- 1 GiB, batch-broadcast of a [L,T] 0/1 map.
// softmax monotone -> top_k(softmax(tv)) idx == top_k(tv) idx; idx < D=768 so
// `% L` is identity -> rows l >= 768 are all zero (80% of output).
//
// Roofline: 1.074 GB mandatory writes; memset sustains ~6.5 TB/s -> ~165 us
// floor for the fill + ~12 us for topk/zero/launches.

#define B_DIM    32
#define L_DIM    4096
#define D_DIM    768
#define T_TOPICS 2048
#define K_TOP    16

#define WORDS_PER_ROW (T_TOPICS / 32)            // 64 u32 per l-row
#define BITMAP_WORDS  (D_DIM * WORDS_PER_ROW)    // 49152 words = 192 KiB
#define PLANE4   (L_DIM * (T_TOPICS / 4))        // float4 per batch plane = 2,097,152
#define BM_CHUNKS (D_DIM * (T_TOPICS / 4) / 1024) // chunks (1024 float4) in rows [0,768) = 384
#define ALL_CHUNKS (PLANE4 / 1024)               // chunks per plane = 2048

typedef float f32x4 __attribute__((ext_vector_type(4)));

__global__ void zero_bitmap_kernel(uint32_t* __restrict__ bm) {
    int i = blockIdx.x * blockDim.x + threadIdx.x;
    if (i < BITMAP_WORDS) bm[i] = 0u;
}

// One wave per topic; 16x wave-argmax (tie -> smaller index, = jax top_k),
// set bit (l=idx, t=topic) in the [D_DIM][T_TOPICS] bitmap.
__global__ void topk_kernel(const float* __restrict__ tv, uint32_t* __restrict__ bm) {
    const int t    = blockIdx.x;
    const int lane = threadIdx.x;
    const float* __restrict__ row = tv + (size_t)t * D_DIM;

    float v[D_DIM / 64];                 // 12 values, idx = lane + j*64
    #pragma unroll
    for (int j = 0; j < D_DIM / 64; ++j) v[j] = row[lane + j * 64];

    for (int k = 0; k < K_TOP; ++k) {
        float bv = v[0];
        int   bj = 0;
        #pragma unroll
        for (int j = 1; j < D_DIM / 64; ++j) {
            if (v[j] > bv) { bv = v[j]; bj = j; }
        }
        float cv = bv;
        int   ci = lane + bj * 64;
        #pragma unroll
        for (int off = 32; off > 0; off >>= 1) {
            float ov = __shfl_xor(cv, off);
            int   oi = __shfl_xor(ci, off);
            if (ov > cv || (ov == cv && oi < ci)) { cv = ov; ci = oi; }
        }
        if ((ci & 63) == lane) v[ci >> 6] = -INFINITY;
        if (lane == 0) {
            atomicOr(&bm[ci * WORDS_PER_ROW + (t >> 5)], 1u << (t & 31));
        }
    }
}

// Fused fill: grid (2048 chunks, 32 batches), 256 threads, 4 float4/thread.
// Chunk c < 384 -> bitmap region (l < 768): 1 hot-L2 dword load per 64 B.
// Chunk c >= 384 -> pure zero stream. Branch is block-uniform (no divergence).
// All output stores nontemporal: 1 GiB pure stream, never re-read -> skip L2
// write-allocate churn.
__global__ __launch_bounds__(256) void fill_kernel(const uint32_t* __restrict__ bm,
                                                   f32x4* __restrict__ out) {
    const unsigned c = blockIdx.x;                       // 0..2047 within plane
    f32x4* p = out + (size_t)blockIdx.y * PLANE4 + c * 1024u + threadIdx.x;

    if (c >= (unsigned)BM_CHUNKS) {
        const f32x4 z = {0.f, 0.f, 0.f, 0.f};
        __builtin_nontemporal_store(z, p);
        __builtin_nontemporal_store(z, p + 256);
        __builtin_nontemporal_store(z, p + 512);
        __builtin_nontemporal_store(z, p + 768);
    } else {
        const unsigned base = c * 1024u + threadIdx.x;
        #pragma unroll
        for (int s = 0; s < 4; ++s) {
            const unsigned idx = base + s * 256u;        // < 393,216 -> l < 768
            const int l  = (int)(idx >> 9);
            const int t4 = (int)(idx & 511u);
            const uint32_t w  = bm[l * WORDS_PER_ROW + (t4 >> 3)];
            const int sh = (t4 & 7) * 4;
            f32x4 val;
            val.x = ((w >> (sh + 0)) & 1u) ? 1.0f : 0.0f;
            val.y = ((w >> (sh + 1)) & 1u) ? 1.0f : 0.0f;
            val.z = ((w >> (sh + 2)) & 1u) ? 1.0f : 0.0f;
            val.w = ((w >> (sh + 3)) & 1u) ? 1.0f : 0.0f;
            __builtin_nontemporal_store(val, p + s * 256);
        }
    }
}

extern "C" void kernel_launch(void* const* d_in, const int* in_sizes, int n_in,
                              void* d_out, int out_size, void* d_ws, size_t ws_size,
                              hipStream_t stream) {
    const float* tv  = (const float*)d_in[1];   // topic_vectors [T, D]
    f32x4*       out = (f32x4*)d_out;           // [B, L, T] f32
    uint32_t*    bm  = (uint32_t*)d_ws;         // 192 KiB bitmap

    hipLaunchKernelGGL(zero_bitmap_kernel,
                       dim3((BITMAP_WORDS + 255) / 256), dim3(256), 0, stream, bm);
    hipLaunchKernelGGL(topk_kernel,
                       dim3(T_TOPICS), dim3(64), 0, stream, tv, bm);
    hipLaunchKernelGGL(fill_kernel,
                       dim3(ALL_CHUNKS, B_DIM), dim3(256), 0, stream, bm, out);
}